// Round 4
// baseline (589.769 us; speedup 1.0000x reference)
//
#include <hip/hip_runtime.h>
#include <hip/hip_fp16.h>

#define DHW (128*128*128)

typedef unsigned int u32x4 __attribute__((ext_vector_type(4)));

// Kernel 1: per-batch rotation matrix from im_feat @ pos_w.T + pos_b.
// R = rot_y(mu) @ rot_x(rho) =
//   [ cm,  sm*sr, -sm*cr ]
//   [ 0,   cr,     sr    ]
//   [ sm, -cm*sr,  cm*cr ]
__global__ void compute_R_kernel(const float* __restrict__ im_feat,
                                 const float* __restrict__ pos_w,
                                 const float* __restrict__ pos_b,
                                 float* __restrict__ Rout) {
    int b = blockIdx.x;
    int t = threadIdx.x;
    const float* f = im_feat + b * 512;
    float s0 = 0.f, s1 = 0.f;
    for (int i = t; i < 512; i += 64) {
        float v = f[i];
        s0 = fmaf(v, pos_w[i], s0);        // row 0 -> mu
        s1 = fmaf(v, pos_w[512 + i], s1);  // row 1 -> rho
    }
    for (int off = 32; off > 0; off >>= 1) {
        s0 += __shfl_down(s0, off, 64);
        s1 += __shfl_down(s1, off, 64);
    }
    if (t == 0) {
        float mu  = s0 + pos_b[0];
        float rho = s1 + pos_b[1];
        float cm = cosf(mu),  sm = sinf(mu);
        float cr = cosf(rho), sr = sinf(rho);
        float* R = Rout + b * 16;
        R[0] = cm;   R[1] = sm * sr;  R[2] = -sm * cr;
        R[3] = 0.f;  R[4] = cr;       R[5] = sr;
        R[6] = sm;   R[7] = -cm * sr; R[8] = cm * cr;
    }
}

// Kernel T: x[B,C,DHW] fp32 -> xt[B,DHW] of 4xfp16 (8 B/texel, RTN).
// 2 texels per thread: 4x float2 coalesced loads, one uint4 store.
__global__ __launch_bounds__(256) void transpose_pack_kernel(const float* __restrict__ x,
                                                             uint4* __restrict__ xt) {
    unsigned t = blockIdx.x * 256u + threadIdx.x;    // 2^23 threads total
    unsigned sp2 = t & (DHW / 2 - 1u);               // texel-pair index
    unsigned b = t >> 20;                            // DHW/2 = 2^20 pairs/batch
    const float2* xb = (const float2*)x + (size_t)(b << 2) * (DHW / 2) + sp2;
    float2 a0 = xb[0];
    float2 a1 = xb[DHW / 2];
    float2 a2 = xb[2 * (DHW / 2)];
    float2 a3 = xb[3 * (DHW / 2)];
    uint4 o;
    o.x = (unsigned)__half_as_ushort(__float2half_rn(a0.x)) |
          ((unsigned)__half_as_ushort(__float2half_rn(a1.x)) << 16);
    o.y = (unsigned)__half_as_ushort(__float2half_rn(a2.x)) |
          ((unsigned)__half_as_ushort(__float2half_rn(a3.x)) << 16);
    o.z = (unsigned)__half_as_ushort(__float2half_rn(a0.y)) |
          ((unsigned)__half_as_ushort(__float2half_rn(a1.y)) << 16);
    o.w = (unsigned)__half_as_ushort(__float2half_rn(a2.y)) |
          ((unsigned)__half_as_ushort(__float2half_rn(a3.y)) << 16);
    xt[(size_t)b * (DHW / 2) + sp2] = o;
}

__device__ inline float2 up2(unsigned u) {
    __half2 h = reinterpret_cast<const __half2&>(u);
    return __half22float2(h);
}

// Kernel 2 (fp16-packed path). Wave footprint reshaped to 32(w) x 2(d):
// dz/d(d) ~= R22 ~ +0.9, so the two d-rows' z0 sets nearly coincide ->
// distinct (z,y) rows per gather instruction drops ~29 -> ~13-19, while
// stores stay coalesced (2 x 128 B rows = 4 lines, same as 1 x 256 B).
// Block index is XCD-chunk swizzled: each XCD gets one contiguous batch,
// swept d-slab-major -> live xt window (~33 z-planes ~ 4.3 MB) fits the
// per-XCD 4 MiB L2; no cross-XCD duplication of xt fills.
__global__ __launch_bounds__(256) void sample_kernel_h(const char* __restrict__ xt,
                                                       const float* __restrict__ Rin,
                                                       float* __restrict__ out) {
    unsigned bid = blockIdx.x;
    // HW maps consecutive bid round-robin to XCDs (bid % 8). Give XCD k the
    // k-th contiguous 8192-block chunk (= exactly one batch). 65536 % 8 == 0.
    unsigned wg = ((bid & 7u) << 13) | (bid >> 3);
    int b = (int)(wg >> 13);                         // block-uniform batch
    unsigned lane = threadIdx.x & 63u;
    unsigned i2 = (wg << 2) | (threadIdx.x >> 6);    // global wave index
    int w = (int)(((i2 & 3u) << 5) | (lane & 31u));
    int h = (int)((i2 >> 2) & 127u);
    int d = (int)((((i2 >> 9) & 63u) << 1) | (lane >> 5));
    h = __builtin_amdgcn_readfirstlane(h);           // uniform per wave

    const float* R = Rin + b * 16;
    const float step = 2.0f / 127.0f;
    float X = fmaf((float)w, step, -1.0f);
    float Y = fmaf((float)h, step, -1.0f);
    float Z = fmaf((float)d, step, -1.0f);

    float gx = fmaf(R[0], X, fmaf(R[1], Y, R[2] * Z));
    float gy = fmaf(R[4], Y, R[5] * Z);              // 2 values per wave
    float gz = fmaf(R[6], X, fmaf(R[7], Y, R[8] * Z));

    float ix = fmaf(gx, 64.0f, 63.5f);
    float iy = fmaf(gy, 64.0f, 63.5f);
    float iz = fmaf(gz, 64.0f, 63.5f);

    float fx0 = floorf(ix), fy0 = floorf(iy), fz0 = floorf(iz);
    float fx = ix - fx0, fy = iy - fy0, fz = iz - fz0;
    int ix0 = (int)fx0, iy0 = (int)fy0, iz0 = (int)fz0;
    int ix1 = ix0 + 1, iy1 = iy0 + 1, iz1 = iz0 + 1;

    float wx0 = ((unsigned)ix0 < 128u) ? (1.f - fx) : 0.f;
    float wx1 = ((unsigned)ix1 < 128u) ? fx : 0.f;
    float wy0 = ((unsigned)iy0 < 128u) ? (1.f - fy) : 0.f;
    float wy1 = ((unsigned)iy1 < 128u) ? fy : 0.f;
    float wz0 = ((unsigned)iz0 < 128u) ? (1.f - fz) : 0.f;
    float wz1 = ((unsigned)iz1 < 128u) ? fz : 0.f;

    unsigned spatial = (((unsigned)(d * 128 + h)) << 7) | (unsigned)w;
    float* ob = out + (size_t)(b << 2) * DHW + spatial;

    // whole-sample OOB: write zeros, no gathers.
    if ((wx0 + wx1) * (wy0 + wy1) * (wz0 + wz1) == 0.f) {
        __builtin_nontemporal_store(0.f, ob);
        __builtin_nontemporal_store(0.f, ob + DHW);
        __builtin_nontemporal_store(0.f, ob + 2 * DHW);
        __builtin_nontemporal_store(0.f, ob + 3 * DHW);
        return;
    }

    int yc0 = min(max(iy0, 0), 127), yc1 = min(max(iy1, 0), 127);
    int zc0 = min(max(iz0, 0), 127), zc1 = min(max(iz1, 0), 127);

    // x window base: texels {base, base+1} always in-row, 8B-aligned.
    int base = min(max(ix0, 0), 126);
    float sw0 = (base == ix0 ? wx0 : 0.f) + (base == ix1 ? wx1 : 0.f);
    float sw1 = (base + 1 == ix0 ? wx0 : 0.f) + (base + 1 == ix1 ? wx1 : 0.f);

    const char* xb = xt + (size_t)b * (DHW * 8);
    unsigned o00 = (((unsigned)(zc0 * 128 + yc0) << 7) + (unsigned)base) << 3;
    unsigned o01 = (((unsigned)(zc0 * 128 + yc1) << 7) + (unsigned)base) << 3;
    unsigned o10 = (((unsigned)(zc1 * 128 + yc0) << 7) + (unsigned)base) << 3;
    unsigned o11 = (((unsigned)(zc1 * 128 + yc1) << 7) + (unsigned)base) << 3;

    u32x4 q0, q1, q2, q3;
    asm volatile("global_load_dwordx4 %0, %1, off" : "=v"(q0) : "v"(xb + o00));
    asm volatile("global_load_dwordx4 %0, %1, off" : "=v"(q1) : "v"(xb + o01));
    asm volatile("global_load_dwordx4 %0, %1, off" : "=v"(q2) : "v"(xb + o10));
    asm volatile("global_load_dwordx4 %0, %1, off" : "=v"(q3) : "v"(xb + o11));
    asm volatile("s_waitcnt vmcnt(0)" ::: "memory");
    __builtin_amdgcn_sched_barrier(0);

    float w00 = wz0 * wy0, w01 = wz0 * wy1, w10 = wz1 * wy0, w11 = wz1 * wy1;

    float a0 = 0.f, a1 = 0.f, a2 = 0.f, a3 = 0.f;
    {   // (z0,y0): q = {c01@s0, c23@s0, c01@s1, c23@s1}
        float ws0 = sw0 * w00, ws1 = sw1 * w00;
        float2 p0 = up2(q0.x), p1 = up2(q0.y), p2 = up2(q0.z), p3 = up2(q0.w);
        a0 = fmaf(p0.x, ws0, fmaf(p2.x, ws1, a0));
        a1 = fmaf(p0.y, ws0, fmaf(p2.y, ws1, a1));
        a2 = fmaf(p1.x, ws0, fmaf(p3.x, ws1, a2));
        a3 = fmaf(p1.y, ws0, fmaf(p3.y, ws1, a3));
    }
    {   // (z0,y1)
        float ws0 = sw0 * w01, ws1 = sw1 * w01;
        float2 p0 = up2(q1.x), p1 = up2(q1.y), p2 = up2(q1.z), p3 = up2(q1.w);
        a0 = fmaf(p0.x, ws0, fmaf(p2.x, ws1, a0));
        a1 = fmaf(p0.y, ws0, fmaf(p2.y, ws1, a1));
        a2 = fmaf(p1.x, ws0, fmaf(p3.x, ws1, a2));
        a3 = fmaf(p1.y, ws0, fmaf(p3.y, ws1, a3));
    }
    {   // (z1,y0)
        float ws0 = sw0 * w10, ws1 = sw1 * w10;
        float2 p0 = up2(q2.x), p1 = up2(q2.y), p2 = up2(q2.z), p3 = up2(q2.w);
        a0 = fmaf(p0.x, ws0, fmaf(p2.x, ws1, a0));
        a1 = fmaf(p0.y, ws0, fmaf(p2.y, ws1, a1));
        a2 = fmaf(p1.x, ws0, fmaf(p3.x, ws1, a2));
        a3 = fmaf(p1.y, ws0, fmaf(p3.y, ws1, a3));
    }
    {   // (z1,y1)
        float ws0 = sw0 * w11, ws1 = sw1 * w11;
        float2 p0 = up2(q3.x), p1 = up2(q3.y), p2 = up2(q3.z), p3 = up2(q3.w);
        a0 = fmaf(p0.x, ws0, fmaf(p2.x, ws1, a0));
        a1 = fmaf(p0.y, ws0, fmaf(p2.y, ws1, a1));
        a2 = fmaf(p1.x, ws0, fmaf(p3.x, ws1, a2));
        a3 = fmaf(p1.y, ws0, fmaf(p3.y, ws1, a3));
    }

    __builtin_nontemporal_store(a0, ob);
    __builtin_nontemporal_store(a1, ob + DHW);
    __builtin_nontemporal_store(a2, ob + 2 * DHW);
    __builtin_nontemporal_store(a3, ob + 3 * DHW);
}

// Fallback (verified R1 kernel): direct fp32 gather from [B,C,DHW] layout.
__global__ __launch_bounds__(256) void sample_kernel(const float* __restrict__ x,
                                                     const float* __restrict__ Rin,
                                                     float* __restrict__ out) {
    unsigned bid = blockIdx.x;
    int b = (int)(bid >> 13);
    unsigned spatial = ((bid & 8191u) << 8) | threadIdx.x;

    int w = spatial & 127;
    int h = (spatial >> 7) & 127;
    int d = spatial >> 14;

    const float* R = Rin + b * 16;
    const float step = 2.0f / 127.0f;
    float X = fmaf((float)w, step, -1.0f);
    float Y = fmaf((float)h, step, -1.0f);
    float Z = fmaf((float)d, step, -1.0f);

    float gx = fmaf(R[0], X, fmaf(R[1], Y, R[2] * Z));
    float gy = fmaf(R[4], Y, R[5] * Z);
    float gz = fmaf(R[6], X, fmaf(R[7], Y, R[8] * Z));

    float ix = fmaf(gx, 64.0f, 63.5f);
    float iy = fmaf(gy, 64.0f, 63.5f);
    float iz = fmaf(gz, 64.0f, 63.5f);

    float fx0 = floorf(ix), fy0 = floorf(iy), fz0 = floorf(iz);
    float fx = ix - fx0, fy = iy - fy0, fz = iz - fz0;
    int ix0 = (int)fx0, iy0 = (int)fy0, iz0 = (int)fz0;
    int ix1 = ix0 + 1, iy1 = iy0 + 1, iz1 = iz0 + 1;

    float wx0 = ((unsigned)ix0 < 128u) ? (1.f - fx) : 0.f;
    float wx1 = ((unsigned)ix1 < 128u) ? fx : 0.f;
    float wy0 = ((unsigned)iy0 < 128u) ? (1.f - fy) : 0.f;
    float wy1 = ((unsigned)iy1 < 128u) ? fy : 0.f;
    float wz0 = ((unsigned)iz0 < 128u) ? (1.f - fz) : 0.f;
    float wz1 = ((unsigned)iz1 < 128u) ? fz : 0.f;

    float* ob = out + (size_t)(b << 2) * DHW + spatial;

    if ((wx0 + wx1) * (wy0 + wy1) * (wz0 + wz1) == 0.f) {
        __builtin_nontemporal_store(0.f, ob);
        __builtin_nontemporal_store(0.f, ob + DHW);
        __builtin_nontemporal_store(0.f, ob + 2 * DHW);
        __builtin_nontemporal_store(0.f, ob + 3 * DHW);
        return;
    }

    int xc0 = min(max(ix0, 0), 127), xc1 = min(max(ix1, 0), 127);
    int yc0 = min(max(iy0, 0), 127), yc1 = min(max(iy1, 0), 127);
    int zc0 = min(max(iz0, 0), 127), zc1 = min(max(iz1, 0), 127);

    int r00 = (zc0 * 128 + yc0) * 128;
    int r01 = (zc0 * 128 + yc1) * 128;
    int r10 = (zc1 * 128 + yc0) * 128;
    int r11 = (zc1 * 128 + yc1) * 128;

    int o0 = r00 + xc0, o1 = r00 + xc1;
    int o2 = r01 + xc0, o3 = r01 + xc1;
    int o4 = r10 + xc0, o5 = r10 + xc1;
    int o6 = r11 + xc0, o7 = r11 + xc1;

    const float* xb = x + (size_t)(b << 2) * DHW;

    float v[4][8];
#pragma unroll
    for (int c = 0; c < 4; ++c) {
        const float* xc = xb + (size_t)c * DHW;
        v[c][0] = xc[o0]; v[c][1] = xc[o1];
        v[c][2] = xc[o2]; v[c][3] = xc[o3];
        v[c][4] = xc[o4]; v[c][5] = xc[o5];
        v[c][6] = xc[o6]; v[c][7] = xc[o7];
    }

    float w00 = wz0 * wy0, w01 = wz0 * wy1, w10 = wz1 * wy0, w11 = wz1 * wy1;

#pragma unroll
    for (int c = 0; c < 4; ++c) {
        float acc;
        acc  = (v[c][0] * wx0 + v[c][1] * wx1) * w00;
        acc += (v[c][2] * wx0 + v[c][3] * wx1) * w01;
        acc += (v[c][4] * wx0 + v[c][5] * wx1) * w10;
        acc += (v[c][6] * wx0 + v[c][7] * wx1) * w11;
        __builtin_nontemporal_store(acc, ob + (size_t)c * DHW);
    }
}

extern "C" void kernel_launch(void* const* d_in, const int* in_sizes, int n_in,
                              void* d_out, int out_size, void* d_ws, size_t ws_size,
                              hipStream_t stream) {
    const float* x       = (const float*)d_in[0];
    const float* im_feat = (const float*)d_in[1];
    const float* pos_w   = (const float*)d_in[2];
    const float* pos_b   = (const float*)d_in[3];
    float* out = (float*)d_out;

    float* Rws = (float*)d_ws;                       // 8 * 16 floats
    const size_t XT_OFF = 1024;                      // keeps xt 16B-aligned
    size_t need = XT_OFF + (size_t)8 * DHW * 8 + 64; // fp16-packed xt + pad

    compute_R_kernel<<<8, 64, 0, stream>>>(im_feat, pos_w, pos_b, Rws);

    int total = 8 * DHW;
    if (ws_size >= need) {
        uint4* xt = (uint4*)((char*)d_ws + XT_OFF);
        transpose_pack_kernel<<<total / 512, 256, 0, stream>>>(x, xt);
        sample_kernel_h<<<total / 256, 256, 0, stream>>>((const char*)xt, Rws, out);
    } else {
        sample_kernel<<<total / 256, 256, 0, stream>>>(x, Rws, out);
    }
}

// Round 5
// 530.169 us; speedup vs baseline: 1.1124x; 1.1124x over previous
//
#include <hip/hip_runtime.h>
#include <hip/hip_fp16.h>

#define DHW (128*128*128)

typedef unsigned int u32x4 __attribute__((ext_vector_type(4)));

// Kernel 1: per-batch rotation matrix from im_feat @ pos_w.T + pos_b.
// R = rot_y(mu) @ rot_x(rho) =
//   [ cm,  sm*sr, -sm*cr ]
//   [ 0,   cr,     sr    ]
//   [ sm, -cm*sr,  cm*cr ]
__global__ void compute_R_kernel(const float* __restrict__ im_feat,
                                 const float* __restrict__ pos_w,
                                 const float* __restrict__ pos_b,
                                 float* __restrict__ Rout) {
    int b = blockIdx.x;
    int t = threadIdx.x;
    const float* f = im_feat + b * 512;
    float s0 = 0.f, s1 = 0.f;
    for (int i = t; i < 512; i += 64) {
        float v = f[i];
        s0 = fmaf(v, pos_w[i], s0);        // row 0 -> mu
        s1 = fmaf(v, pos_w[512 + i], s1);  // row 1 -> rho
    }
    for (int off = 32; off > 0; off >>= 1) {
        s0 += __shfl_down(s0, off, 64);
        s1 += __shfl_down(s1, off, 64);
    }
    if (t == 0) {
        float mu  = s0 + pos_b[0];
        float rho = s1 + pos_b[1];
        float cm = cosf(mu),  sm = sinf(mu);
        float cr = cosf(rho), sr = sinf(rho);
        float* R = Rout + b * 16;
        R[0] = cm;   R[1] = sm * sr;  R[2] = -sm * cr;
        R[3] = 0.f;  R[4] = cr;       R[5] = sr;
        R[6] = sm;   R[7] = -cm * sr; R[8] = cm * cr;
    }
}

// Kernel T (R3-verified): x[B,C,DHW] fp32 -> xt[B,DHW] of 4xfp16 (8 B/texel).
__global__ __launch_bounds__(256) void transpose_pack_kernel(const float* __restrict__ x,
                                                             uint2* __restrict__ xt) {
    unsigned tid = blockIdx.x * 256u + threadIdx.x;
    unsigned spatial = tid & (DHW - 1u);
    unsigned b = tid >> 21;
    const float* xb = x + (size_t)(b << 2) * DHW + spatial;
    float a0 = xb[0];
    float a1 = xb[DHW];
    float a2 = xb[2u * DHW];
    float a3 = xb[3u * DHW];
    unsigned lo = (unsigned)__half_as_ushort(__float2half_rn(a0)) |
                  ((unsigned)__half_as_ushort(__float2half_rn(a1)) << 16);
    unsigned hi = (unsigned)__half_as_ushort(__float2half_rn(a2)) |
                  ((unsigned)__half_as_ushort(__float2half_rn(a3)) << 16);
    xt[(size_t)tid] = make_uint2(lo, hi);
}

__device__ inline float2 up2(unsigned u) {
    __half2 h = reinterpret_cast<const __half2&>(u);
    return __half22float2(h);
}

// Kernel 2 (fp16-packed path). SINGLE isolated change vs the verified R3
// kernel: wave footprint reshaped 64x1 -> 32(w) x 2(d). dz/d(d) ~= R22 ~ +0.9,
// so the paired d-row's z0 set nearly coincides with the first's -> distinct
// (z,y) rows per gather instruction drops ~26 -> ~17 (the TA/L1 line
// transactions that bound this kernel), while stores stay coalesced
// (2 x 128 B segments = 4 lines/store, same as 1 x 256 B).
// Block mapping is LINEAR (R4's XCD-chunk swizzle caused per-XCD load
// imbalance via batch-dependent OOB fractions -> 51% occupancy; reverted).
__global__ __launch_bounds__(256) void sample_kernel_h(const char* __restrict__ xt,
                                                       const float* __restrict__ Rin,
                                                       float* __restrict__ out) {
    unsigned wg = blockIdx.x;
    int b = (int)(wg >> 13);                         // block-uniform batch
    unsigned lane = threadIdx.x & 63u;
    unsigned i2 = (wg << 2) | (threadIdx.x >> 6);    // global wave index
    int w = (int)(((i2 & 3u) << 5) | (lane & 31u));
    int h = (int)((i2 >> 2) & 127u);
    int d = (int)((((i2 >> 9) & 63u) << 1) | (lane >> 5));
    h = __builtin_amdgcn_readfirstlane(h);           // uniform per wave

    const float* R = Rin + b * 16;
    const float step = 2.0f / 127.0f;
    float X = fmaf((float)w, step, -1.0f);
    float Y = fmaf((float)h, step, -1.0f);
    float Z = fmaf((float)d, step, -1.0f);

    float gx = fmaf(R[0], X, fmaf(R[1], Y, R[2] * Z));
    float gy = fmaf(R[4], Y, R[5] * Z);              // 2 values per wave
    float gz = fmaf(R[6], X, fmaf(R[7], Y, R[8] * Z));

    float ix = fmaf(gx, 64.0f, 63.5f);
    float iy = fmaf(gy, 64.0f, 63.5f);
    float iz = fmaf(gz, 64.0f, 63.5f);

    float fx0 = floorf(ix), fy0 = floorf(iy), fz0 = floorf(iz);
    float fx = ix - fx0, fy = iy - fy0, fz = iz - fz0;
    int ix0 = (int)fx0, iy0 = (int)fy0, iz0 = (int)fz0;
    int ix1 = ix0 + 1, iy1 = iy0 + 1, iz1 = iz0 + 1;

    float wx0 = ((unsigned)ix0 < 128u) ? (1.f - fx) : 0.f;
    float wx1 = ((unsigned)ix1 < 128u) ? fx : 0.f;
    float wy0 = ((unsigned)iy0 < 128u) ? (1.f - fy) : 0.f;
    float wy1 = ((unsigned)iy1 < 128u) ? fy : 0.f;
    float wz0 = ((unsigned)iz0 < 128u) ? (1.f - fz) : 0.f;
    float wz1 = ((unsigned)iz1 < 128u) ? fz : 0.f;

    unsigned spatial = (((unsigned)(d * 128 + h)) << 7) | (unsigned)w;
    float* ob = out + (size_t)(b << 2) * DHW + spatial;

    // whole-sample OOB: write zeros, no gathers.
    if ((wx0 + wx1) * (wy0 + wy1) * (wz0 + wz1) == 0.f) {
        __builtin_nontemporal_store(0.f, ob);
        __builtin_nontemporal_store(0.f, ob + DHW);
        __builtin_nontemporal_store(0.f, ob + 2 * DHW);
        __builtin_nontemporal_store(0.f, ob + 3 * DHW);
        return;
    }

    int yc0 = min(max(iy0, 0), 127), yc1 = min(max(iy1, 0), 127);
    int zc0 = min(max(iz0, 0), 127), zc1 = min(max(iz1, 0), 127);

    // x window base: texels {base, base+1} always in-row, 8B-aligned.
    int base = min(max(ix0, 0), 126);
    float sw0 = (base == ix0 ? wx0 : 0.f) + (base == ix1 ? wx1 : 0.f);
    float sw1 = (base + 1 == ix0 ? wx0 : 0.f) + (base + 1 == ix1 ? wx1 : 0.f);

    const char* xb = xt + (size_t)b * (DHW * 8);
    unsigned o00 = (((unsigned)(zc0 * 128 + yc0) << 7) + (unsigned)base) << 3;
    unsigned o01 = (((unsigned)(zc0 * 128 + yc1) << 7) + (unsigned)base) << 3;
    unsigned o10 = (((unsigned)(zc1 * 128 + yc0) << 7) + (unsigned)base) << 3;
    unsigned o11 = (((unsigned)(zc1 * 128 + yc1) << 7) + (unsigned)base) << 3;

    u32x4 q0, q1, q2, q3;
    asm volatile("global_load_dwordx4 %0, %1, off" : "=v"(q0) : "v"(xb + o00));
    asm volatile("global_load_dwordx4 %0, %1, off" : "=v"(q1) : "v"(xb + o01));
    asm volatile("global_load_dwordx4 %0, %1, off" : "=v"(q2) : "v"(xb + o10));
    asm volatile("global_load_dwordx4 %0, %1, off" : "=v"(q3) : "v"(xb + o11));
    asm volatile("s_waitcnt vmcnt(0)" ::: "memory");
    __builtin_amdgcn_sched_barrier(0);

    float w00 = wz0 * wy0, w01 = wz0 * wy1, w10 = wz1 * wy0, w11 = wz1 * wy1;

    float a0 = 0.f, a1 = 0.f, a2 = 0.f, a3 = 0.f;
    {   // (z0,y0): q = {c01@s0, c23@s0, c01@s1, c23@s1}
        float ws0 = sw0 * w00, ws1 = sw1 * w00;
        float2 p0 = up2(q0.x), p1 = up2(q0.y), p2 = up2(q0.z), p3 = up2(q0.w);
        a0 = fmaf(p0.x, ws0, fmaf(p2.x, ws1, a0));
        a1 = fmaf(p0.y, ws0, fmaf(p2.y, ws1, a1));
        a2 = fmaf(p1.x, ws0, fmaf(p3.x, ws1, a2));
        a3 = fmaf(p1.y, ws0, fmaf(p3.y, ws1, a3));
    }
    {   // (z0,y1)
        float ws0 = sw0 * w01, ws1 = sw1 * w01;
        float2 p0 = up2(q1.x), p1 = up2(q1.y), p2 = up2(q1.z), p3 = up2(q1.w);
        a0 = fmaf(p0.x, ws0, fmaf(p2.x, ws1, a0));
        a1 = fmaf(p0.y, ws0, fmaf(p2.y, ws1, a1));
        a2 = fmaf(p1.x, ws0, fmaf(p3.x, ws1, a2));
        a3 = fmaf(p1.y, ws0, fmaf(p3.y, ws1, a3));
    }
    {   // (z1,y0)
        float ws0 = sw0 * w10, ws1 = sw1 * w10;
        float2 p0 = up2(q2.x), p1 = up2(q2.y), p2 = up2(q2.z), p3 = up2(q2.w);
        a0 = fmaf(p0.x, ws0, fmaf(p2.x, ws1, a0));
        a1 = fmaf(p0.y, ws0, fmaf(p2.y, ws1, a1));
        a2 = fmaf(p1.x, ws0, fmaf(p3.x, ws1, a2));
        a3 = fmaf(p1.y, ws0, fmaf(p3.y, ws1, a3));
    }
    {   // (z1,y1)
        float ws0 = sw0 * w11, ws1 = sw1 * w11;
        float2 p0 = up2(q3.x), p1 = up2(q3.y), p2 = up2(q3.z), p3 = up2(q3.w);
        a0 = fmaf(p0.x, ws0, fmaf(p2.x, ws1, a0));
        a1 = fmaf(p0.y, ws0, fmaf(p2.y, ws1, a1));
        a2 = fmaf(p1.x, ws0, fmaf(p3.x, ws1, a2));
        a3 = fmaf(p1.y, ws0, fmaf(p3.y, ws1, a3));
    }

    __builtin_nontemporal_store(a0, ob);
    __builtin_nontemporal_store(a1, ob + DHW);
    __builtin_nontemporal_store(a2, ob + 2 * DHW);
    __builtin_nontemporal_store(a3, ob + 3 * DHW);
}

// Fallback (verified R1 kernel): direct fp32 gather from [B,C,DHW] layout.
__global__ __launch_bounds__(256) void sample_kernel(const float* __restrict__ x,
                                                     const float* __restrict__ Rin,
                                                     float* __restrict__ out) {
    unsigned bid = blockIdx.x;
    int b = (int)(bid >> 13);
    unsigned spatial = ((bid & 8191u) << 8) | threadIdx.x;

    int w = spatial & 127;
    int h = (spatial >> 7) & 127;
    int d = spatial >> 14;

    const float* R = Rin + b * 16;
    const float step = 2.0f / 127.0f;
    float X = fmaf((float)w, step, -1.0f);
    float Y = fmaf((float)h, step, -1.0f);
    float Z = fmaf((float)d, step, -1.0f);

    float gx = fmaf(R[0], X, fmaf(R[1], Y, R[2] * Z));
    float gy = fmaf(R[4], Y, R[5] * Z);
    float gz = fmaf(R[6], X, fmaf(R[7], Y, R[8] * Z));

    float ix = fmaf(gx, 64.0f, 63.5f);
    float iy = fmaf(gy, 64.0f, 63.5f);
    float iz = fmaf(gz, 64.0f, 63.5f);

    float fx0 = floorf(ix), fy0 = floorf(iy), fz0 = floorf(iz);
    float fx = ix - fx0, fy = iy - fy0, fz = iz - fz0;
    int ix0 = (int)fx0, iy0 = (int)fy0, iz0 = (int)fz0;
    int ix1 = ix0 + 1, iy1 = iy0 + 1, iz1 = iz0 + 1;

    float wx0 = ((unsigned)ix0 < 128u) ? (1.f - fx) : 0.f;
    float wx1 = ((unsigned)ix1 < 128u) ? fx : 0.f;
    float wy0 = ((unsigned)iy0 < 128u) ? (1.f - fy) : 0.f;
    float wy1 = ((unsigned)iy1 < 128u) ? fy : 0.f;
    float wz0 = ((unsigned)iz0 < 128u) ? (1.f - fz) : 0.f;
    float wz1 = ((unsigned)iz1 < 128u) ? fz : 0.f;

    float* ob = out + (size_t)(b << 2) * DHW + spatial;

    if ((wx0 + wx1) * (wy0 + wy1) * (wz0 + wz1) == 0.f) {
        __builtin_nontemporal_store(0.f, ob);
        __builtin_nontemporal_store(0.f, ob + DHW);
        __builtin_nontemporal_store(0.f, ob + 2 * DHW);
        __builtin_nontemporal_store(0.f, ob + 3 * DHW);
        return;
    }

    int xc0 = min(max(ix0, 0), 127), xc1 = min(max(ix1, 0), 127);
    int yc0 = min(max(iy0, 0), 127), yc1 = min(max(iy1, 0), 127);
    int zc0 = min(max(iz0, 0), 127), zc1 = min(max(iz1, 0), 127);

    int r00 = (zc0 * 128 + yc0) * 128;
    int r01 = (zc0 * 128 + yc1) * 128;
    int r10 = (zc1 * 128 + yc0) * 128;
    int r11 = (zc1 * 128 + yc1) * 128;

    int o0 = r00 + xc0, o1 = r00 + xc1;
    int o2 = r01 + xc0, o3 = r01 + xc1;
    int o4 = r10 + xc0, o5 = r10 + xc1;
    int o6 = r11 + xc0, o7 = r11 + xc1;

    const float* xb = x + (size_t)(b << 2) * DHW;

    float v[4][8];
#pragma unroll
    for (int c = 0; c < 4; ++c) {
        const float* xc = xb + (size_t)c * DHW;
        v[c][0] = xc[o0]; v[c][1] = xc[o1];
        v[c][2] = xc[o2]; v[c][3] = xc[o3];
        v[c][4] = xc[o4]; v[c][5] = xc[o5];
        v[c][6] = xc[o6]; v[c][7] = xc[o7];
    }

    float w00 = wz0 * wy0, w01 = wz0 * wy1, w10 = wz1 * wy0, w11 = wz1 * wy1;

#pragma unroll
    for (int c = 0; c < 4; ++c) {
        float acc;
        acc  = (v[c][0] * wx0 + v[c][1] * wx1) * w00;
        acc += (v[c][2] * wx0 + v[c][3] * wx1) * w01;
        acc += (v[c][4] * wx0 + v[c][5] * wx1) * w10;
        acc += (v[c][6] * wx0 + v[c][7] * wx1) * w11;
        __builtin_nontemporal_store(acc, ob + (size_t)c * DHW);
    }
}

extern "C" void kernel_launch(void* const* d_in, const int* in_sizes, int n_in,
                              void* d_out, int out_size, void* d_ws, size_t ws_size,
                              hipStream_t stream) {
    const float* x       = (const float*)d_in[0];
    const float* im_feat = (const float*)d_in[1];
    const float* pos_w   = (const float*)d_in[2];
    const float* pos_b   = (const float*)d_in[3];
    float* out = (float*)d_out;

    float* Rws = (float*)d_ws;                       // 8 * 16 floats
    const size_t XT_OFF = 1024;                      // keeps xt 16B-aligned
    size_t need = XT_OFF + (size_t)8 * DHW * 8 + 64; // fp16-packed xt + pad

    compute_R_kernel<<<8, 64, 0, stream>>>(im_feat, pos_w, pos_b, Rws);

    int total = 8 * DHW;
    if (ws_size >= need) {
        uint2* xt = (uint2*)((char*)d_ws + XT_OFF);
        transpose_pack_kernel<<<total / 256, 256, 0, stream>>>(x, xt);
        sample_kernel_h<<<total / 256, 256, 0, stream>>>((const char*)xt, Rws, out);
    } else {
        sample_kernel<<<total / 256, 256, 0, stream>>>(x, Rws, out);
    }
}